// Round 7
// baseline (600.828 us; speedup 1.0000x reference)
//
#include <hip/hip_runtime.h>
#include <hip/hip_bf16.h>

// CrossBandWindowAttentionWav — R7: barrier-free full-K GEMM chunks.
// prep -> qkv (per-window: stage x, q-chunk, stage cx, k + 4 v-chunks; v
// stored transposed pre-swizzled) -> attn (vt via global_load_lds, swapped
// QK/PV, in-reg softmax, att pre-swizzled) -> proj (att via global_load_lds,
// 4 n-chunks, fp32 out). A staged once per block (48KB, full K=384); B read
// per-fragment from L2-hot weights; zero barriers inside compute sweeps.

typedef __attribute__((ext_vector_type(8))) short short8;
typedef __attribute__((ext_vector_type(4))) float f32x4;

__device__ __forceinline__ f32x4 mfma_b16(short8 a, short8 b, f32x4 c) {
  return __builtin_amdgcn_mfma_f32_16x16x32_bf16(a, b, c, 0, 0, 0);
}

__device__ __forceinline__ unsigned short f2bf(float x) {
  unsigned u = __builtin_bit_cast(unsigned, x);
  u = (u + 0x7fffu + ((u >> 16) & 1u)) >> 16;  // RNE; inputs finite
  return (unsigned short)u;
}

__device__ __forceinline__ unsigned pack2(float a, float b) {
  return (unsigned)f2bf(a) | ((unsigned)f2bf(b) << 16);
}

// chunk swizzle for 768B rows (48 x 16B chunks): XOR low3 of chunk with row
__device__ __forceinline__ int swz48(int c, int r) {
  return (c & ~7) | ((c ^ r) & 7);
}

// async global->LDS, 16B/lane; LDS base wave-uniform, global addr per-lane
__device__ __forceinline__ void gl_lds16(const char* g, char* l) {
  __builtin_amdgcn_global_load_lds(
      (const __attribute__((address_space(1))) unsigned int*)g,
      (__attribute__((address_space(3))) unsigned int*)l, 16, 0, 0);
}

// ---------------------------------------------------------------- prep ------
__global__ void prep_k(const float* __restrict__ Wq, const float* __restrict__ Wk,
                       const float* __restrict__ Wv, const float* __restrict__ Wp,
                       const float* __restrict__ rpb, const int* __restrict__ rpi,
                       const float* __restrict__ bk, const float* __restrict__ bv,
                       unsigned short* __restrict__ Wq_t, unsigned short* __restrict__ Wkv_t,
                       unsigned short* __restrict__ Wp_t, float* __restrict__ bias6,
                       float* __restrict__ bias_kv) {
  const int T0 = 96 * 384, T1 = 480 * 384, T2 = 384 * 384, T3 = 6 * 4096, T4 = 480;
  int total = T0 + T1 + T2 + T3 + T4;
  for (int i = blockIdx.x * blockDim.x + threadIdx.x; i < total;
       i += gridDim.x * blockDim.x) {
    int r = i;
    if (r < T0) {                       // Wq_t[n][k] = Wq[k][n]
      int n = r / 384, k = r % 384;
      Wq_t[r] = f2bf(Wq[k * 96 + n]);
    } else if ((r -= T0) < T1) {        // rows 0..95 = Wk^T, 96..479 = Wv^T
      int n = r / 384, k = r % 384;
      Wkv_t[r] = f2bf(n < 96 ? Wk[k * 96 + n] : Wv[k * 384 + (n - 96)]);
    } else if ((r -= T1) < T2) {
      int n = r / 384, k = r % 384;
      Wp_t[r] = f2bf(Wp[k * 384 + n]);
    } else if ((r -= T2) < T3) {        // bias6[h][i][j] = rpb[rpi[i][j]][h]
      int h = r >> 12, ij = r & 4095;
      bias6[r] = rpb[rpi[ij] * 6 + h];
    } else {
      r -= T3;
      bias_kv[r] = (r < 96) ? bk[r] : bv[r - 96];
    }
  }
}

// ---- 64x96 GEMM chunk over full K=384; A in LDS (swizzled 768B rows),
// B = bf16 NxK weights read per-fragment from global (L2-hot). No barriers.
__device__ __forceinline__ void compute96(const char* lds,
                                          const unsigned short* __restrict__ Bt,
                                          int wm, int wn, int lr, int lg,
                                          f32x4 (&acc)[2][3]) {
#pragma unroll
  for (int kt = 0; kt < 6; ++kt)
#pragma unroll
    for (int ks = 0; ks < 2; ++ks) {
      short8 a[2];
#pragma unroll
      for (int mf = 0; mf < 2; ++mf) {
        const int row = wm + mf * 16 + lr;
        a[mf] = *reinterpret_cast<const short8*>(
            lds + row * 768 + swz48(kt * 8 + ks * 4 + lg, row) * 16);
      }
#pragma unroll
      for (int nf = 0; nf < 3; ++nf) {
        const short8 b = *reinterpret_cast<const short8*>(
            Bt + (size_t)(wn + nf * 16 + lr) * 384 + kt * 64 + ks * 32 + lg * 8);
        acc[0][nf] = mfma_b16(a[0], b, acc[0][nf]);
        acc[1][nf] = mfma_b16(a[1], b, acc[1][nf]);
      }
    }
}

// ----------------------------------------------------------------- qkv ------
__global__ __launch_bounds__(256, 3) void qkv_k(
    const float* __restrict__ x, const float* __restrict__ cx,
    const unsigned short* __restrict__ Wq_t, const unsigned short* __restrict__ Wkv_t,
    const float* __restrict__ bq, const float* __restrict__ bkv,
    unsigned short* __restrict__ q_buf, unsigned short* __restrict__ k_buf,
    unsigned short* __restrict__ vt_buf) {
  __shared__ char lds[49152];
  const int tid = threadIdx.x, lane = tid & 63, wid = tid >> 6;
  const int lr = lane & 15, lg = lane >> 4;
  const int wm = (wid >> 1) * 32, wn = (wid & 1) * 48;
  const int w = blockIdx.x;

  auto stage = [&](const float* A) {  // fp32 [64][384] -> bf16 LDS, swizzled
#pragma unroll
    for (int it = 0; it < 12; ++it) {
      const int e = (it * 256 + tid) * 8;
      const int r = e / 384, col = e % 384;
      const float4 v0 = *reinterpret_cast<const float4*>(A + (size_t)r * 384 + col);
      const float4 v1 = *reinterpret_cast<const float4*>(A + (size_t)r * 384 + col + 4);
      uint4 pk;
      pk.x = pack2(v0.x, v0.y); pk.y = pack2(v0.z, v0.w);
      pk.z = pack2(v1.x, v1.y); pk.w = pack2(v1.z, v1.w);
      *reinterpret_cast<uint4*>(lds + r * 768 + swz48(col >> 3, r) * 16) = pk;
    }
  };

  // q = x @ Wq^T + bq
  stage(x + (size_t)w * 24576);
  __syncthreads();
  f32x4 aq[2][3];
#pragma unroll
  for (int i = 0; i < 2; ++i)
#pragma unroll
    for (int j = 0; j < 3; ++j) aq[i][j] = (f32x4){0.f, 0.f, 0.f, 0.f};
  compute96(lds, Wq_t, wm, wn, lr, lg, aq);
  __syncthreads();  // all q LDS-reads done before cx overwrites
  stage(cx + (size_t)w * 24576);
  // q stores overlap the cx stage
#pragma unroll
  for (int mf = 0; mf < 2; ++mf)
#pragma unroll
    for (int nf = 0; nf < 3; ++nf) {
      const int col = wn + nf * 16 + lr;
      const float bb = bq[col];
#pragma unroll
      for (int r = 0; r < 4; ++r)
        q_buf[(size_t)(w * 64 + wm + mf * 16 + lg * 4 + r) * 96 + col] =
            f2bf(aq[mf][nf][r] + bb);
    }
  __syncthreads();

  // k = cx @ Wk^T + bk
  {
    f32x4 ak[2][3];
#pragma unroll
    for (int i = 0; i < 2; ++i)
#pragma unroll
      for (int j = 0; j < 3; ++j) ak[i][j] = (f32x4){0.f, 0.f, 0.f, 0.f};
    compute96(lds, Wkv_t, wm, wn, lr, lg, ak);
#pragma unroll
    for (int mf = 0; mf < 2; ++mf)
#pragma unroll
      for (int nf = 0; nf < 3; ++nf) {
        const int col = wn + nf * 16 + lr;
        const float bb = bkv[col];
#pragma unroll
        for (int r = 0; r < 4; ++r)
          k_buf[(size_t)(w * 64 + wm + mf * 16 + lg * 4 + r) * 96 + col] =
              f2bf(ak[mf][nf][r] + bb);
      }
  }
  // v chunks -> vt (win, d, tok) bf16, chunk-swizzled; acc rows = 4
  // consecutive tokens at one d -> contiguous 8B in-lane store.
#pragma unroll
  for (int vc = 0; vc < 4; ++vc) {
    f32x4 av[2][3];
#pragma unroll
    for (int i = 0; i < 2; ++i)
#pragma unroll
      for (int j = 0; j < 3; ++j) av[i][j] = (f32x4){0.f, 0.f, 0.f, 0.f};
    compute96(lds, Wkv_t + (size_t)(96 + vc * 96) * 384, wm, wn, lr, lg, av);
#pragma unroll
    for (int mf = 0; mf < 2; ++mf)
#pragma unroll
      for (int nf = 0; nf < 3; ++nf) {
        const int d = vc * 96 + wn + nf * 16 + lr;
        const float bb = bkv[96 + d];
        const int tok0 = wm + mf * 16 + lg * 4;
        uint2 st;
        st.x = pack2(av[mf][nf][0] + bb, av[mf][nf][1] + bb);
        st.y = pack2(av[mf][nf][2] + bb, av[mf][nf][3] + bb);
        const int c = tok0 >> 3;
        *reinterpret_cast<uint2*>((char*)vt_buf + (size_t)w * 49152 + d * 128 +
                                  ((c ^ (d & 7)) << 4) + ((tok0 * 2) & 8)) = st;
      }
  }
}

// ----------------------------------------------------------- attention ------
// 1 block = 1 window, 4 waves; wave handles 16 query rows (iq = wid*16+lr).
// Swapped-operand QK^T and PV; softmax fully in-register (shfl 16/32).
__global__ __launch_bounds__(256, 2) void attn_k(
    const unsigned short* __restrict__ q_buf, const unsigned short* __restrict__ k_buf,
    const unsigned short* __restrict__ vt_buf, const float* __restrict__ bias6,
    const float* __restrict__ mask, unsigned short* __restrict__ att_buf) {
  __shared__ char lds[57344];  // vt [384][128B] swz @0; P [64][128B] swz @49152
  const int tid = threadIdx.x, lane = tid & 63, wid = tid >> 6;
  const int lr = lane & 15, lg = lane >> 4;
  const int w = blockIdx.x;

  const char* vsrc = (const char*)vt_buf + (size_t)w * 49152;  // pre-swizzled
#pragma unroll
  for (int j = 0; j < 12; ++j) {
    const int off = (wid * 12 + j) * 1024;
    gl_lds16(vsrc + off + lane * 16, lds + off);
  }
  __syncthreads();

  char* Plds = lds + 49152;
  const float* mw = mask + (size_t)(w & 1023) * 4096;
  const int iq = wid * 16 + lr;  // this lane's query row

  for (int h = 0; h < 6; ++h) {
    // S^T = mfma(K, Q): lane gets S[j][iq], j = tj*16 + lg*4 + r
    short8 qa = {0, 0, 0, 0, 0, 0, 0, 0};
    if (lg < 2)
      qa = *reinterpret_cast<const short8*>(
          q_buf + (size_t)(w * 64 + iq) * 96 + h * 16 + lg * 8);
    float sv[4][4];
#pragma unroll
    for (int tj = 0; tj < 4; ++tj) {
      short8 kf = {0, 0, 0, 0, 0, 0, 0, 0};
      if (lg < 2)
        kf = *reinterpret_cast<const short8*>(
            k_buf + (size_t)(w * 64 + tj * 16 + lr) * 96 + h * 16 + lg * 8);
      f32x4 z = {0.f, 0.f, 0.f, 0.f};
      f32x4 s = mfma_b16(kf, qa, z);
      const int j0 = tj * 16 + lg * 4;
      const float4 bi = *reinterpret_cast<const float4*>(bias6 + h * 4096 + iq * 64 + j0);
      const float4 mk = *reinterpret_cast<const float4*>(mw + iq * 64 + j0);
      sv[tj][0] = s[0] * 0.25f + bi.x + mk.x;
      sv[tj][1] = s[1] * 0.25f + bi.y + mk.y;
      sv[tj][2] = s[2] * 0.25f + bi.z + mk.z;
      sv[tj][3] = s[3] * 0.25f + bi.w + mk.w;
    }
    float mx = sv[0][0];
#pragma unroll
    for (int tj = 0; tj < 4; ++tj)
#pragma unroll
      for (int r = 0; r < 4; ++r) mx = fmaxf(mx, sv[tj][r]);
    mx = fmaxf(mx, __shfl_xor(mx, 16));
    mx = fmaxf(mx, __shfl_xor(mx, 32));
    float sum = 0.f;
#pragma unroll
    for (int tj = 0; tj < 4; ++tj)
#pragma unroll
      for (int r = 0; r < 4; ++r) {
        sv[tj][r] = __expf(sv[tj][r] - mx);
        sum += sv[tj][r];
      }
    sum += __shfl_xor(sum, 16);
    sum += __shfl_xor(sum, 32);
    const float inv = 1.0f / sum;
    // P row iq -> LDS (swizzled); written & read by this wave only
#pragma unroll
    for (int tj = 0; tj < 4; ++tj) {
      const int c = tj * 2 + (lg >> 1);
      uint2 st;
      st.x = pack2(sv[tj][0] * inv, sv[tj][1] * inv);
      st.y = pack2(sv[tj][2] * inv, sv[tj][3] * inv);
      *reinterpret_cast<uint2*>(Plds + iq * 128 + ((c ^ (iq & 7)) << 4) +
                                (lg & 1) * 8) = st;
    }
    short8 pa[2];
#pragma unroll
    for (int ks = 0; ks < 2; ++ks)
      pa[ks] = *reinterpret_cast<const short8*>(
          Plds + iq * 128 + (((ks * 4 + lg) ^ (iq & 7)) << 4));
    // att[iq][d] via mfma(V^T, P): lane gets d = h*64 + td*16 + lg*4 + r
#pragma unroll
    for (int td = 0; td < 4; ++td) {
      f32x4 o = {0.f, 0.f, 0.f, 0.f};
#pragma unroll
      for (int ks = 0; ks < 2; ++ks) {
        const int d = h * 64 + td * 16 + lr;
        short8 vb = *reinterpret_cast<const short8*>(
            lds + d * 128 + (((ks * 4 + lg) ^ (d & 7)) << 4));
        o = mfma_b16(vb, pa[ks], o);
      }
      const int c0 = h * 64 + td * 16 + lg * 4;
      uint2 st;
      st.x = pack2(o[0], o[1]);
      st.y = pack2(o[2], o[3]);
      *reinterpret_cast<uint2*>((char*)att_buf + (size_t)(w * 64 + iq) * 768 +
                                swz48(c0 >> 3, iq) * 16 + ((c0 * 2) & 8)) = st;
    }
  }
}

// ---------------------------------------------------------------- proj ------
__global__ __launch_bounds__(256, 3) void proj_k(
    const unsigned short* __restrict__ att_buf, const unsigned short* __restrict__ Wp_t,
    const float* __restrict__ bp, float* __restrict__ out) {
  __shared__ char lds[49152];
  const int tid = threadIdx.x, lane = tid & 63, wid = tid >> 6;
  const int lr = lane & 15, lg = lane >> 4;
  const int wm = (wid >> 1) * 32, wn = (wid & 1) * 48;
  const int w = blockIdx.x;

  const char* asrc = (const char*)att_buf + (size_t)w * 49152;  // pre-swizzled
#pragma unroll
  for (int j = 0; j < 12; ++j) {
    const int off = (wid * 12 + j) * 1024;
    gl_lds16(asrc + off + lane * 16, lds + off);
  }
  __syncthreads();

#pragma unroll
  for (int nc = 0; nc < 4; ++nc) {
    f32x4 acc[2][3];
#pragma unroll
    for (int i = 0; i < 2; ++i)
#pragma unroll
      for (int j = 0; j < 3; ++j) acc[i][j] = (f32x4){0.f, 0.f, 0.f, 0.f};
    compute96(lds, Wp_t + (size_t)(nc * 96) * 384, wm, wn, lr, lg, acc);
#pragma unroll
    for (int mf = 0; mf < 2; ++mf)
#pragma unroll
      for (int nf = 0; nf < 3; ++nf) {
        const int col = nc * 96 + wn + nf * 16 + lr;
        const float bb = bp[col];
#pragma unroll
        for (int r = 0; r < 4; ++r)
          out[(size_t)(w * 64 + wm + mf * 16 + lg * 4 + r) * 384 + col] =
              acc[mf][nf][r] + bb;
      }
  }
}

// -------------------------------------------------------------- launch ------
extern "C" void kernel_launch(void* const* d_in, const int* in_sizes, int n_in,
                              void* d_out, int out_size, void* d_ws, size_t ws_size,
                              hipStream_t stream) {
  const float* x    = (const float*)d_in[0];
  const float* cx   = (const float*)d_in[1];
  const int*   rpi  = (const int*)d_in[2];
  const float* mask = (const float*)d_in[3];
  const float* Wq   = (const float*)d_in[4];
  const float* bq   = (const float*)d_in[5];
  const float* Wk   = (const float*)d_in[6];
  const float* bk   = (const float*)d_in[7];
  const float* Wv   = (const float*)d_in[8];
  const float* bv   = (const float*)d_in[9];
  const float* Wp   = (const float*)d_in[10];
  const float* bp   = (const float*)d_in[11];
  const float* rpb  = (const float*)d_in[12];

  char* ws = (char*)d_ws;
  unsigned short* Wq_t   = (unsigned short*)(ws + 0);        //  73,728 B
  unsigned short* Wkv_t  = (unsigned short*)(ws + 73728);    // 368,640 B
  unsigned short* Wp_t   = (unsigned short*)(ws + 442368);   // 294,912 B
  float*          bias6  = (float*)(ws + 737280);            //  98,304 B
  float*          biaskv = (float*)(ws + 835584);            //   1,920 B
  const size_t MB = 1u << 20;
  unsigned short* q_buf  = (unsigned short*)(ws + MB);                   // 25,165,824 B
  unsigned short* k_buf  = (unsigned short*)(ws + MB + 25165824u);       // 25,165,824 B
  unsigned short* vt_buf = (unsigned short*)(ws + MB + 50331648u);       // 100,663,296 B
  unsigned short* att    = (unsigned short*)(ws + MB + 150994944u);      // 100,663,296 B

  prep_k<<<256, 256, 0, stream>>>(Wq, Wk, Wv, Wp, rpb, rpi, bk, bv,
                                  Wq_t, Wkv_t, Wp_t, bias6, biaskv);
  qkv_k<<<2048, 256, 0, stream>>>(x, cx, Wq_t, Wkv_t, bq, biaskv,
                                  q_buf, k_buf, vt_buf);
  attn_k<<<2048, 256, 0, stream>>>(q_buf, k_buf, vt_buf, bias6, mask, att);
  proj_k<<<2048, 256, 0, stream>>>(att, Wp_t, bp, (float*)d_out);
}

// Round 8
// 578.545 us; speedup vs baseline: 1.0385x; 1.0385x over previous
//
#include <hip/hip_runtime.h>
#include <hip/hip_bf16.h>

// CrossBandWindowAttentionWav — R8 = R7 + register-pipelined B fragments.
// prep -> qkv (per-window: stage x, q-chunk, stage cx, k + 4 v-chunks; v
// stored transposed pre-swizzled) -> attn (vt via global_load_lds, swapped
// QK/PV, in-reg softmax, att pre-swizzled) -> proj (att via global_load_lds,
// 4 n-chunks, fp32 out). A staged once per block (48KB, full K=384); B read
// from L2-hot weights with a 1-ktile register prefetch pipeline (bcur/bnext,
// static indices) so each MFMA cluster hides the next tile's L2 latency.

typedef __attribute__((ext_vector_type(8))) short short8;
typedef __attribute__((ext_vector_type(4))) float f32x4;

__device__ __forceinline__ f32x4 mfma_b16(short8 a, short8 b, f32x4 c) {
  return __builtin_amdgcn_mfma_f32_16x16x32_bf16(a, b, c, 0, 0, 0);
}

__device__ __forceinline__ unsigned short f2bf(float x) {
  unsigned u = __builtin_bit_cast(unsigned, x);
  u = (u + 0x7fffu + ((u >> 16) & 1u)) >> 16;  // RNE; inputs finite
  return (unsigned short)u;
}

__device__ __forceinline__ unsigned pack2(float a, float b) {
  return (unsigned)f2bf(a) | ((unsigned)f2bf(b) << 16);
}

// chunk swizzle for 768B rows (48 x 16B chunks): XOR low3 of chunk with row
__device__ __forceinline__ int swz48(int c, int r) {
  return (c & ~7) | ((c ^ r) & 7);
}

// async global->LDS, 16B/lane; LDS base wave-uniform, global addr per-lane
__device__ __forceinline__ void gl_lds16(const char* g, char* l) {
  __builtin_amdgcn_global_load_lds(
      (const __attribute__((address_space(1))) unsigned int*)g,
      (__attribute__((address_space(3))) unsigned int*)l, 16, 0, 0);
}

// ---------------------------------------------------------------- prep ------
__global__ void prep_k(const float* __restrict__ Wq, const float* __restrict__ Wk,
                       const float* __restrict__ Wv, const float* __restrict__ Wp,
                       const float* __restrict__ rpb, const int* __restrict__ rpi,
                       const float* __restrict__ bk, const float* __restrict__ bv,
                       unsigned short* __restrict__ Wq_t, unsigned short* __restrict__ Wkv_t,
                       unsigned short* __restrict__ Wp_t, float* __restrict__ bias6,
                       float* __restrict__ bias_kv) {
  const int T0 = 96 * 384, T1 = 480 * 384, T2 = 384 * 384, T3 = 6 * 4096, T4 = 480;
  int total = T0 + T1 + T2 + T3 + T4;
  for (int i = blockIdx.x * blockDim.x + threadIdx.x; i < total;
       i += gridDim.x * blockDim.x) {
    int r = i;
    if (r < T0) {                       // Wq_t[n][k] = Wq[k][n]
      int n = r / 384, k = r % 384;
      Wq_t[r] = f2bf(Wq[k * 96 + n]);
    } else if ((r -= T0) < T1) {        // rows 0..95 = Wk^T, 96..479 = Wv^T
      int n = r / 384, k = r % 384;
      Wkv_t[r] = f2bf(n < 96 ? Wk[k * 96 + n] : Wv[k * 384 + (n - 96)]);
    } else if ((r -= T1) < T2) {
      int n = r / 384, k = r % 384;
      Wp_t[r] = f2bf(Wp[k * 384 + n]);
    } else if ((r -= T2) < T3) {        // bias6[h][i][j] = rpb[rpi[i][j]][h]
      int h = r >> 12, ij = r & 4095;
      bias6[r] = rpb[rpi[ij] * 6 + h];
    } else {
      r -= T3;
      bias_kv[r] = (r < 96) ? bk[r] : bv[r - 96];
    }
  }
}

// ---- 64x96 GEMM chunk over full K=384; A in LDS (swizzled 768B rows),
// B = bf16 NxK weights from global (L2-hot) with 1-ktile register prefetch.
__device__ __forceinline__ void compute96(const char* lds,
                                          const unsigned short* __restrict__ Bt,
                                          int wm, int wn, int lr, int lg,
                                          f32x4 (&acc)[2][3]) {
  const unsigned short* Bbase = Bt + (size_t)(wn + lr) * 384 + lg * 8;
  short8 bcur[6], bnext[6];
#pragma unroll
  for (int ks = 0; ks < 2; ++ks)
#pragma unroll
    for (int nf = 0; nf < 3; ++nf)
      bcur[ks * 3 + nf] = *reinterpret_cast<const short8*>(
          Bbase + (size_t)nf * 16 * 384 + ks * 32);
#pragma unroll
  for (int kt = 0; kt < 6; ++kt) {
    if (kt < 5) {
#pragma unroll
      for (int ks = 0; ks < 2; ++ks)
#pragma unroll
        for (int nf = 0; nf < 3; ++nf)
          bnext[ks * 3 + nf] = *reinterpret_cast<const short8*>(
              Bbase + (size_t)nf * 16 * 384 + (kt + 1) * 64 + ks * 32);
    }
#pragma unroll
    for (int ks = 0; ks < 2; ++ks) {
      short8 a[2];
#pragma unroll
      for (int mf = 0; mf < 2; ++mf) {
        const int row = wm + mf * 16 + lr;
        a[mf] = *reinterpret_cast<const short8*>(
            lds + row * 768 + swz48(kt * 8 + ks * 4 + lg, row) * 16);
      }
#pragma unroll
      for (int nf = 0; nf < 3; ++nf) {
        acc[0][nf] = mfma_b16(a[0], bcur[ks * 3 + nf], acc[0][nf]);
        acc[1][nf] = mfma_b16(a[1], bcur[ks * 3 + nf], acc[1][nf]);
      }
    }
#pragma unroll
    for (int i = 0; i < 6; ++i) bcur[i] = bnext[i];
  }
}

// ----------------------------------------------------------------- qkv ------
__global__ __launch_bounds__(256, 3) void qkv_k(
    const float* __restrict__ x, const float* __restrict__ cx,
    const unsigned short* __restrict__ Wq_t, const unsigned short* __restrict__ Wkv_t,
    const float* __restrict__ bq, const float* __restrict__ bkv,
    unsigned short* __restrict__ q_buf, unsigned short* __restrict__ k_buf,
    unsigned short* __restrict__ vt_buf) {
  __shared__ char lds[49152];
  const int tid = threadIdx.x, lane = tid & 63, wid = tid >> 6;
  const int lr = lane & 15, lg = lane >> 4;
  const int wm = (wid >> 1) * 32, wn = (wid & 1) * 48;
  const int w = blockIdx.x;

  auto stage = [&](const float* A) {  // fp32 [64][384] -> bf16 LDS, swizzled
#pragma unroll
    for (int it = 0; it < 12; ++it) {
      const int e = (it * 256 + tid) * 8;
      const int r = e / 384, col = e % 384;
      const float4 v0 = *reinterpret_cast<const float4*>(A + (size_t)r * 384 + col);
      const float4 v1 = *reinterpret_cast<const float4*>(A + (size_t)r * 384 + col + 4);
      uint4 pk;
      pk.x = pack2(v0.x, v0.y); pk.y = pack2(v0.z, v0.w);
      pk.z = pack2(v1.x, v1.y); pk.w = pack2(v1.z, v1.w);
      *reinterpret_cast<uint4*>(lds + r * 768 + swz48(col >> 3, r) * 16) = pk;
    }
  };

  // q = x @ Wq^T + bq
  stage(x + (size_t)w * 24576);
  __syncthreads();
  f32x4 aq[2][3];
#pragma unroll
  for (int i = 0; i < 2; ++i)
#pragma unroll
    for (int j = 0; j < 3; ++j) aq[i][j] = (f32x4){0.f, 0.f, 0.f, 0.f};
  compute96(lds, Wq_t, wm, wn, lr, lg, aq);
  __syncthreads();  // all q LDS-reads done before cx overwrites
  stage(cx + (size_t)w * 24576);
  // q stores overlap the cx stage
#pragma unroll
  for (int mf = 0; mf < 2; ++mf)
#pragma unroll
    for (int nf = 0; nf < 3; ++nf) {
      const int col = wn + nf * 16 + lr;
      const float bb = bq[col];
#pragma unroll
      for (int r = 0; r < 4; ++r)
        q_buf[(size_t)(w * 64 + wm + mf * 16 + lg * 4 + r) * 96 + col] =
            f2bf(aq[mf][nf][r] + bb);
    }
  __syncthreads();

  // k = cx @ Wk^T + bk
  {
    f32x4 ak[2][3];
#pragma unroll
    for (int i = 0; i < 2; ++i)
#pragma unroll
      for (int j = 0; j < 3; ++j) ak[i][j] = (f32x4){0.f, 0.f, 0.f, 0.f};
    compute96(lds, Wkv_t, wm, wn, lr, lg, ak);
#pragma unroll
    for (int mf = 0; mf < 2; ++mf)
#pragma unroll
      for (int nf = 0; nf < 3; ++nf) {
        const int col = wn + nf * 16 + lr;
        const float bb = bkv[col];
#pragma unroll
        for (int r = 0; r < 4; ++r)
          k_buf[(size_t)(w * 64 + wm + mf * 16 + lg * 4 + r) * 96 + col] =
              f2bf(ak[mf][nf][r] + bb);
      }
  }
  // v chunks -> vt (win, d, tok) bf16, chunk-swizzled; acc rows = 4
  // consecutive tokens at one d -> contiguous 8B in-lane store.
#pragma unroll 1
  for (int vc = 0; vc < 4; ++vc) {
    f32x4 av[2][3];
#pragma unroll
    for (int i = 0; i < 2; ++i)
#pragma unroll
      for (int j = 0; j < 3; ++j) av[i][j] = (f32x4){0.f, 0.f, 0.f, 0.f};
    compute96(lds, Wkv_t + (size_t)(96 + vc * 96) * 384, wm, wn, lr, lg, av);
#pragma unroll
    for (int mf = 0; mf < 2; ++mf)
#pragma unroll
      for (int nf = 0; nf < 3; ++nf) {
        const int d = vc * 96 + wn + nf * 16 + lr;
        const float bb = bkv[96 + d];
        const int tok0 = wm + mf * 16 + lg * 4;
        uint2 st;
        st.x = pack2(av[mf][nf][0] + bb, av[mf][nf][1] + bb);
        st.y = pack2(av[mf][nf][2] + bb, av[mf][nf][3] + bb);
        const int c = tok0 >> 3;
        *reinterpret_cast<uint2*>((char*)vt_buf + (size_t)w * 49152 + d * 128 +
                                  ((c ^ (d & 7)) << 4) + ((tok0 * 2) & 8)) = st;
      }
  }
}

// ----------------------------------------------------------- attention ------
// 1 block = 1 window, 4 waves; wave handles 16 query rows (iq = wid*16+lr).
// Swapped-operand QK^T and PV; softmax fully in-register (shfl 16/32).
__global__ __launch_bounds__(256, 2) void attn_k(
    const unsigned short* __restrict__ q_buf, const unsigned short* __restrict__ k_buf,
    const unsigned short* __restrict__ vt_buf, const float* __restrict__ bias6,
    const float* __restrict__ mask, unsigned short* __restrict__ att_buf) {
  __shared__ char lds[57344];  // vt [384][128B] swz @0; P [64][128B] swz @49152
  const int tid = threadIdx.x, lane = tid & 63, wid = tid >> 6;
  const int lr = lane & 15, lg = lane >> 4;
  const int w = blockIdx.x;

  const char* vsrc = (const char*)vt_buf + (size_t)w * 49152;  // pre-swizzled
#pragma unroll
  for (int j = 0; j < 12; ++j) {
    const int off = (wid * 12 + j) * 1024;
    gl_lds16(vsrc + off + lane * 16, lds + off);
  }
  __syncthreads();

  char* Plds = lds + 49152;
  const float* mw = mask + (size_t)(w & 1023) * 4096;
  const int iq = wid * 16 + lr;  // this lane's query row

  for (int h = 0; h < 6; ++h) {
    // S^T = mfma(K, Q): lane gets S[j][iq], j = tj*16 + lg*4 + r
    short8 qa = {0, 0, 0, 0, 0, 0, 0, 0};
    if (lg < 2)
      qa = *reinterpret_cast<const short8*>(
          q_buf + (size_t)(w * 64 + iq) * 96 + h * 16 + lg * 8);
    float sv[4][4];
#pragma unroll
    for (int tj = 0; tj < 4; ++tj) {
      short8 kf = {0, 0, 0, 0, 0, 0, 0, 0};
      if (lg < 2)
        kf = *reinterpret_cast<const short8*>(
            k_buf + (size_t)(w * 64 + tj * 16 + lr) * 96 + h * 16 + lg * 8);
      f32x4 z = {0.f, 0.f, 0.f, 0.f};
      f32x4 s = mfma_b16(kf, qa, z);
      const int j0 = tj * 16 + lg * 4;
      const float4 bi = *reinterpret_cast<const float4*>(bias6 + h * 4096 + iq * 64 + j0);
      const float4 mk = *reinterpret_cast<const float4*>(mw + iq * 64 + j0);
      sv[tj][0] = s[0] * 0.25f + bi.x + mk.x;
      sv[tj][1] = s[1] * 0.25f + bi.y + mk.y;
      sv[tj][2] = s[2] * 0.25f + bi.z + mk.z;
      sv[tj][3] = s[3] * 0.25f + bi.w + mk.w;
    }
    float mx = sv[0][0];
#pragma unroll
    for (int tj = 0; tj < 4; ++tj)
#pragma unroll
      for (int r = 0; r < 4; ++r) mx = fmaxf(mx, sv[tj][r]);
    mx = fmaxf(mx, __shfl_xor(mx, 16));
    mx = fmaxf(mx, __shfl_xor(mx, 32));
    float sum = 0.f;
#pragma unroll
    for (int tj = 0; tj < 4; ++tj)
#pragma unroll
      for (int r = 0; r < 4; ++r) {
        sv[tj][r] = __expf(sv[tj][r] - mx);
        sum += sv[tj][r];
      }
    sum += __shfl_xor(sum, 16);
    sum += __shfl_xor(sum, 32);
    const float inv = 1.0f / sum;
    // P row iq -> LDS (swizzled); written & read by this wave only
#pragma unroll
    for (int tj = 0; tj < 4; ++tj) {
      const int c = tj * 2 + (lg >> 1);
      uint2 st;
      st.x = pack2(sv[tj][0] * inv, sv[tj][1] * inv);
      st.y = pack2(sv[tj][2] * inv, sv[tj][3] * inv);
      *reinterpret_cast<uint2*>(Plds + iq * 128 + ((c ^ (iq & 7)) << 4) +
                                (lg & 1) * 8) = st;
    }
    short8 pa[2];
#pragma unroll
    for (int ks = 0; ks < 2; ++ks)
      pa[ks] = *reinterpret_cast<const short8*>(
          Plds + iq * 128 + (((ks * 4 + lg) ^ (iq & 7)) << 4));
    // att[iq][d] via mfma(V^T, P): lane gets d = h*64 + td*16 + lg*4 + r
#pragma unroll
    for (int td = 0; td < 4; ++td) {
      f32x4 o = {0.f, 0.f, 0.f, 0.f};
#pragma unroll
      for (int ks = 0; ks < 2; ++ks) {
        const int d = h * 64 + td * 16 + lr;
        short8 vb = *reinterpret_cast<const short8*>(
            lds + d * 128 + (((ks * 4 + lg) ^ (d & 7)) << 4));
        o = mfma_b16(vb, pa[ks], o);
      }
      const int c0 = h * 64 + td * 16 + lg * 4;
      uint2 st;
      st.x = pack2(o[0], o[1]);
      st.y = pack2(o[2], o[3]);
      *reinterpret_cast<uint2*>((char*)att_buf + (size_t)(w * 64 + iq) * 768 +
                                swz48(c0 >> 3, iq) * 16 + ((c0 * 2) & 8)) = st;
    }
  }
}

// ---------------------------------------------------------------- proj ------
__global__ __launch_bounds__(256, 3) void proj_k(
    const unsigned short* __restrict__ att_buf, const unsigned short* __restrict__ Wp_t,
    const float* __restrict__ bp, float* __restrict__ out) {
  __shared__ char lds[49152];
  const int tid = threadIdx.x, lane = tid & 63, wid = tid >> 6;
  const int lr = lane & 15, lg = lane >> 4;
  const int wm = (wid >> 1) * 32, wn = (wid & 1) * 48;
  const int w = blockIdx.x;

  const char* asrc = (const char*)att_buf + (size_t)w * 49152;  // pre-swizzled
#pragma unroll
  for (int j = 0; j < 12; ++j) {
    const int off = (wid * 12 + j) * 1024;
    gl_lds16(asrc + off + lane * 16, lds + off);
  }
  __syncthreads();

#pragma unroll 1
  for (int nc = 0; nc < 4; ++nc) {
    f32x4 acc[2][3];
#pragma unroll
    for (int i = 0; i < 2; ++i)
#pragma unroll
      for (int j = 0; j < 3; ++j) acc[i][j] = (f32x4){0.f, 0.f, 0.f, 0.f};
    compute96(lds, Wp_t + (size_t)(nc * 96) * 384, wm, wn, lr, lg, acc);
#pragma unroll
    for (int mf = 0; mf < 2; ++mf)
#pragma unroll
      for (int nf = 0; nf < 3; ++nf) {
        const int col = nc * 96 + wn + nf * 16 + lr;
        const float bb = bp[col];
#pragma unroll
        for (int r = 0; r < 4; ++r)
          out[(size_t)(w * 64 + wm + mf * 16 + lg * 4 + r) * 384 + col] =
              acc[mf][nf][r] + bb;
      }
  }
}

// -------------------------------------------------------------- launch ------
extern "C" void kernel_launch(void* const* d_in, const int* in_sizes, int n_in,
                              void* d_out, int out_size, void* d_ws, size_t ws_size,
                              hipStream_t stream) {
  const float* x    = (const float*)d_in[0];
  const float* cx   = (const float*)d_in[1];
  const int*   rpi  = (const int*)d_in[2];
  const float* mask = (const float*)d_in[3];
  const float* Wq   = (const float*)d_in[4];
  const float* bq   = (const float*)d_in[5];
  const float* Wk   = (const float*)d_in[6];
  const float* bk   = (const float*)d_in[7];
  const float* Wv   = (const float*)d_in[8];
  const float* bv   = (const float*)d_in[9];
  const float* Wp   = (const float*)d_in[10];
  const float* bp   = (const float*)d_in[11];
  const float* rpb  = (const float*)d_in[12];

  char* ws = (char*)d_ws;
  unsigned short* Wq_t   = (unsigned short*)(ws + 0);        //  73,728 B
  unsigned short* Wkv_t  = (unsigned short*)(ws + 73728);    // 368,640 B
  unsigned short* Wp_t   = (unsigned short*)(ws + 442368);   // 294,912 B
  float*          bias6  = (float*)(ws + 737280);            //  98,304 B
  float*          biaskv = (float*)(ws + 835584);            //   1,920 B
  const size_t MB = 1u << 20;
  unsigned short* q_buf  = (unsigned short*)(ws + MB);                   // 25,165,824 B
  unsigned short* k_buf  = (unsigned short*)(ws + MB + 25165824u);       // 25,165,824 B
  unsigned short* vt_buf = (unsigned short*)(ws + MB + 50331648u);       // 100,663,296 B
  unsigned short* att    = (unsigned short*)(ws + MB + 150994944u);      // 100,663,296 B

  prep_k<<<256, 256, 0, stream>>>(Wq, Wk, Wv, Wp, rpb, rpi, bk, bv,
                                  Wq_t, Wkv_t, Wp_t, bias6, biaskv);
  qkv_k<<<2048, 256, 0, stream>>>(x, cx, Wq_t, Wkv_t, bq, biaskv,
                                  q_buf, k_buf, vt_buf);
  attn_k<<<2048, 256, 0, stream>>>(q_buf, k_buf, vt_buf, bias6, mask, att);
  proj_k<<<2048, 256, 0, stream>>>(att, Wp_t, bp, (float*)d_out);
}

// Round 9
// 459.283 us; speedup vs baseline: 1.3082x; 1.2597x over previous
//
#include <hip/hip_runtime.h>
#include <hip/hip_bf16.h>

// CrossBandWindowAttentionWav — R9: max-TLP small-tile GEMM.
// gws_k: BM=64/BN=64/BK=32, 20KB LDS dbuf, reg-staged A/B into 80B-padded
// rows (2-way bank alias = free), 6 blocks/CU (24 waves), XCD swizzle.
// Weights zero-padded so N%64==0 (Wq->128, Wkv->512). attn = R8's proven
// kernel, att written LINEAR. Pipeline: prep -> q -> kv(v pre-swizzled
// transposed) -> attn -> proj.

typedef __attribute__((ext_vector_type(8))) short short8;
typedef __attribute__((ext_vector_type(4))) float f32x4;

__device__ __forceinline__ f32x4 mfma_b16(short8 a, short8 b, f32x4 c) {
  return __builtin_amdgcn_mfma_f32_16x16x32_bf16(a, b, c, 0, 0, 0);
}

__device__ __forceinline__ unsigned short f2bf(float x) {
  return __builtin_bit_cast(unsigned short, __float2bfloat16(x));  // RNE
}

__device__ __forceinline__ unsigned pack2(float a, float b) {
  return (unsigned)f2bf(a) | ((unsigned)f2bf(b) << 16);
}

// chunk swizzle used by attn's vt layout (48/8 x 16B chunks per row)
__device__ __forceinline__ int swz48(int c, int r) {
  return (c & ~7) | ((c ^ r) & 7);
}

__device__ __forceinline__ void gl_lds16(const char* g, char* l) {
  __builtin_amdgcn_global_load_lds(
      (const __attribute__((address_space(1))) unsigned int*)g,
      (__attribute__((address_space(3))) unsigned int*)l, 16, 0, 0);
}

// ---------------------------------------------------------------- prep ------
// Wq_t padded to 128 rows, Wkv_t padded to 512 rows (zeros beyond real N).
__global__ void prep_k(const float* __restrict__ Wq, const float* __restrict__ Wk,
                       const float* __restrict__ Wv, const float* __restrict__ Wp,
                       const float* __restrict__ rpb, const int* __restrict__ rpi,
                       const float* __restrict__ bk, const float* __restrict__ bv,
                       unsigned short* __restrict__ Wq_t, unsigned short* __restrict__ Wkv_t,
                       unsigned short* __restrict__ Wp_t, float* __restrict__ bias6,
                       float* __restrict__ bias_kv) {
  const int T0 = 128 * 384, T1 = 512 * 384, T2 = 384 * 384, T3 = 6 * 4096, T4 = 480;
  int total = T0 + T1 + T2 + T3 + T4;
  for (int i = blockIdx.x * blockDim.x + threadIdx.x; i < total;
       i += gridDim.x * blockDim.x) {
    int r = i;
    if (r < T0) {                       // Wq_t[n][k] = Wq[k][n], n<96 else 0
      int n = r / 384, k = r % 384;
      Wq_t[r] = (n < 96) ? f2bf(Wq[k * 96 + n]) : (unsigned short)0;
    } else if ((r -= T0) < T1) {        // 0..95 Wk^T, 96..479 Wv^T, else 0
      int n = r / 384, k = r % 384;
      Wkv_t[r] = (n < 96) ? f2bf(Wk[k * 96 + n])
                          : (n < 480) ? f2bf(Wv[k * 384 + (n - 96)])
                                      : (unsigned short)0;
    } else if ((r -= T1) < T2) {
      int n = r / 384, k = r % 384;
      Wp_t[r] = f2bf(Wp[k * 384 + n]);
    } else if ((r -= T2) < T3) {        // bias6[h][i][j] = rpb[rpi[i][j]][h]
      int h = r >> 12, ij = r & 4095;
      bias6[r] = rpb[rpi[ij] * 6 + h];
    } else {
      r -= T3;
      bias_kv[r] = (r < 96) ? bk[r] : bv[r - 96];
    }
  }
}

// ---------------------------------------------------------------- GEMM ------
// C[M=131072, N=NX*64] = A[M,384] @ Bt[N,384]^T + bias.  BM=64 BN=64 BK=32.
// grid = NX*2048 XCD-swizzled (adjacent = same m-panel, different n -> same
// XCD L2). LDS 20KB: A dbuf 2x5120 @0, B dbuf 2x5120 @10240; rows padded to
// 80B (2-way bank alias, free). Reg-staged (T14 issue-early/write-late),
// one barrier per K-phase, 12 phases.
// A_F32: A fp32 (cvt during stage) else bf16.
// OUT 0: bf16 [M,96], cols>=96 dropped | 1: fp32 [M,384] | 2: col<96 ->
// k_out[M,96]; 96<=col<480 -> vt_out (win,d,tok) chunk-swizzled bf16.
template <int A_F32, int OUT_MODE, int NX>
__global__ __launch_bounds__(256, 6) void gws_k(
    const void* __restrict__ Av, const unsigned short* __restrict__ Bt,
    const float* __restrict__ bias, void* __restrict__ Outv,
    unsigned short* __restrict__ k_out, unsigned short* __restrict__ vt_out) {
  __shared__ char lds[20480];
  const int tid = threadIdx.x, lane = tid & 63, wid = tid >> 6;
  const int lr = lane & 15, lg = lane >> 4;
  const int g = blockIdx.x;
  const int lg_id = (g & 7) * (NX * 256) + (g >> 3);
  const int my = lg_id / NX, nx = lg_id - my * NX;
  const int m0 = my * 64, n0 = nx * 64;
  const int srow = tid >> 2, sq = tid & 3;  // staging: row, 16B-chunk

  float4 areg0, areg1;   // fp32-A staged regs
  short8 a8reg, breg;    // bf16-A / B staged regs

  auto issue = [&](int kt) {
    if (A_F32) {
      const float* A = (const float*)Av + (size_t)(m0 + srow) * 384 + kt * 32 + sq * 8;
      areg0 = *reinterpret_cast<const float4*>(A);
      areg1 = *reinterpret_cast<const float4*>(A + 4);
    } else {
      a8reg = *reinterpret_cast<const short8*>(
          (const unsigned short*)Av + (size_t)(m0 + srow) * 384 + kt * 32 + sq * 8);
    }
    breg = *reinterpret_cast<const short8*>(
        Bt + (size_t)(n0 + srow) * 384 + kt * 32 + sq * 8);
  };
  auto write = [&](int buf) {
    char* Ab = lds + buf * 5120;
    char* Bb = lds + 10240 + buf * 5120;
    if (A_F32) {
      uint4 pk;
      pk.x = pack2(areg0.x, areg0.y);
      pk.y = pack2(areg0.z, areg0.w);
      pk.z = pack2(areg1.x, areg1.y);
      pk.w = pack2(areg1.z, areg1.w);
      *reinterpret_cast<uint4*>(Ab + srow * 80 + sq * 16) = pk;
    } else {
      *reinterpret_cast<short8*>(Ab + srow * 80 + sq * 16) = a8reg;
    }
    *reinterpret_cast<short8*>(Bb + srow * 80 + sq * 16) = breg;
  };

  f32x4 acc[4];
#pragma unroll
  for (int j = 0; j < 4; ++j) acc[j] = (f32x4){0.f, 0.f, 0.f, 0.f};

  issue(0);
  write(0);
  __syncthreads();
  int cur = 0;
#pragma unroll
  for (int kt = 0; kt < 12; ++kt) {
    if (kt < 11) issue(kt + 1);          // VMEM first (lands during compute+wait)
    {
      const char* Ab = lds + cur * 5120;
      const char* Bb = lds + 10240 + cur * 5120;
      const short8 a = *reinterpret_cast<const short8*>(
          Ab + (wid * 16 + lr) * 80 + lg * 16);
#pragma unroll
      for (int nf = 0; nf < 4; ++nf) {
        const short8 b = *reinterpret_cast<const short8*>(
            Bb + (nf * 16 + lr) * 80 + lg * 16);
        acc[nf] = mfma_b16(a, b, acc[nf]);
      }
    }
    if (kt < 11) write(cur ^ 1);         // vmcnt wait + cvt + ds_write
    __syncthreads();
    cur ^= 1;
  }

  // ---- epilogue: C row = m0 + wid*16 + lg*4 + r, col = n0 + nf*16 + lr
#pragma unroll
  for (int nf = 0; nf < 4; ++nf) {
    const int col = n0 + nf * 16 + lr;
    if (OUT_MODE == 0) {
      if (col < 96) {
        const float bb = bias[col];
#pragma unroll
        for (int r = 0; r < 4; ++r) {
          const int row = m0 + wid * 16 + lg * 4 + r;
          ((unsigned short*)Outv)[(size_t)row * 96 + col] = f2bf(acc[nf][r] + bb);
        }
      }
    } else if (OUT_MODE == 1) {
      const float bb = bias[col];
#pragma unroll
      for (int r = 0; r < 4; ++r) {
        const int row = m0 + wid * 16 + lg * 4 + r;
        ((float*)Outv)[(size_t)row * 384 + col] = acc[nf][r] + bb;
      }
    } else {
      if (col < 96) {
        const float bb = bias[col];
#pragma unroll
        for (int r = 0; r < 4; ++r) {
          const int row = m0 + wid * 16 + lg * 4 + r;
          k_out[(size_t)row * 96 + col] = f2bf(acc[nf][r] + bb);
        }
      } else if (col < 480) {
        const float bb = bias[col];
        const int d = col - 96;
        const int tok0 = wid * 16 + lg * 4;
        uint2 st;
        st.x = pack2(acc[nf][0] + bb, acc[nf][1] + bb);
        st.y = pack2(acc[nf][2] + bb, acc[nf][3] + bb);
        const int c = tok0 >> 3;
        *reinterpret_cast<uint2*>((char*)vt_out + (size_t)my * 49152 + d * 128 +
                                  ((c ^ (d & 7)) << 4) + ((tok0 * 2) & 8)) = st;
      }
    }
  }
}

// ----------------------------------------------------------- attention ------
// 1 block = 1 window, 4 waves; wave handles 16 query rows (iq = wid*16+lr).
// Swapped-operand QK^T and PV; softmax fully in-register (shfl 16/32).
__global__ __launch_bounds__(256, 2) void attn_k(
    const unsigned short* __restrict__ q_buf, const unsigned short* __restrict__ k_buf,
    const unsigned short* __restrict__ vt_buf, const float* __restrict__ bias6,
    const float* __restrict__ mask, unsigned short* __restrict__ att_buf) {
  __shared__ char lds[57344];  // vt [384][128B] swz @0; P [64][128B] swz @49152
  const int tid = threadIdx.x, lane = tid & 63, wid = tid >> 6;
  const int lr = lane & 15, lg = lane >> 4;
  const int w = blockIdx.x;

  const char* vsrc = (const char*)vt_buf + (size_t)w * 49152;  // pre-swizzled
#pragma unroll
  for (int j = 0; j < 12; ++j) {
    const int off = (wid * 12 + j) * 1024;
    gl_lds16(vsrc + off + lane * 16, lds + off);
  }
  __syncthreads();

  char* Plds = lds + 49152;
  const float* mw = mask + (size_t)(w & 1023) * 4096;
  const int iq = wid * 16 + lr;  // this lane's query row

  for (int h = 0; h < 6; ++h) {
    // S^T = mfma(K, Q): lane gets S[j][iq], j = tj*16 + lg*4 + r
    short8 qa = {0, 0, 0, 0, 0, 0, 0, 0};
    if (lg < 2)
      qa = *reinterpret_cast<const short8*>(
          q_buf + (size_t)(w * 64 + iq) * 96 + h * 16 + lg * 8);
    float sv[4][4];
#pragma unroll
    for (int tj = 0; tj < 4; ++tj) {
      short8 kf = {0, 0, 0, 0, 0, 0, 0, 0};
      if (lg < 2)
        kf = *reinterpret_cast<const short8*>(
            k_buf + (size_t)(w * 64 + tj * 16 + lr) * 96 + h * 16 + lg * 8);
      f32x4 z = {0.f, 0.f, 0.f, 0.f};
      f32x4 s = mfma_b16(kf, qa, z);
      const int j0 = tj * 16 + lg * 4;
      const float4 bi = *reinterpret_cast<const float4*>(bias6 + h * 4096 + iq * 64 + j0);
      const float4 mk = *reinterpret_cast<const float4*>(mw + iq * 64 + j0);
      sv[tj][0] = s[0] * 0.25f + bi.x + mk.x;
      sv[tj][1] = s[1] * 0.25f + bi.y + mk.y;
      sv[tj][2] = s[2] * 0.25f + bi.z + mk.z;
      sv[tj][3] = s[3] * 0.25f + bi.w + mk.w;
    }
    float mx = sv[0][0];
#pragma unroll
    for (int tj = 0; tj < 4; ++tj)
#pragma unroll
      for (int r = 0; r < 4; ++r) mx = fmaxf(mx, sv[tj][r]);
    mx = fmaxf(mx, __shfl_xor(mx, 16));
    mx = fmaxf(mx, __shfl_xor(mx, 32));
    float sum = 0.f;
#pragma unroll
    for (int tj = 0; tj < 4; ++tj)
#pragma unroll
      for (int r = 0; r < 4; ++r) {
        sv[tj][r] = __expf(sv[tj][r] - mx);
        sum += sv[tj][r];
      }
    sum += __shfl_xor(sum, 16);
    sum += __shfl_xor(sum, 32);
    const float inv = 1.0f / sum;
    // P row iq -> LDS (swizzled); written & read by this wave only
#pragma unroll
    for (int tj = 0; tj < 4; ++tj) {
      const int c = tj * 2 + (lg >> 1);
      uint2 st;
      st.x = pack2(sv[tj][0] * inv, sv[tj][1] * inv);
      st.y = pack2(sv[tj][2] * inv, sv[tj][3] * inv);
      *reinterpret_cast<uint2*>(Plds + iq * 128 + ((c ^ (iq & 7)) << 4) +
                                (lg & 1) * 8) = st;
    }
    short8 pa[2];
#pragma unroll
    for (int ks = 0; ks < 2; ++ks)
      pa[ks] = *reinterpret_cast<const short8*>(
          Plds + iq * 128 + (((ks * 4 + lg) ^ (iq & 7)) << 4));
    // att[iq][d] via mfma(V^T, P): lane gets d = h*64 + td*16 + lg*4 + r
#pragma unroll
    for (int td = 0; td < 4; ++td) {
      f32x4 o = {0.f, 0.f, 0.f, 0.f};
#pragma unroll
      for (int ks = 0; ks < 2; ++ks) {
        const int d = h * 64 + td * 16 + lr;
        short8 vb = *reinterpret_cast<const short8*>(
            lds + d * 128 + (((ks * 4 + lg) ^ (d & 7)) << 4));
        o = mfma_b16(vb, pa[ks], o);
      }
      const int c0 = h * 64 + td * 16 + lg * 4;
      uint2 st;
      st.x = pack2(o[0], o[1]);
      st.y = pack2(o[2], o[3]);
      // LINEAR att layout [tok][384] bf16 (proj reg-stages it)
      *reinterpret_cast<uint2*>((char*)att_buf + (size_t)(w * 64 + iq) * 768 +
                                c0 * 2) = st;
    }
  }
}

// -------------------------------------------------------------- launch ------
extern "C" void kernel_launch(void* const* d_in, const int* in_sizes, int n_in,
                              void* d_out, int out_size, void* d_ws, size_t ws_size,
                              hipStream_t stream) {
  const float* x    = (const float*)d_in[0];
  const float* cx   = (const float*)d_in[1];
  const int*   rpi  = (const int*)d_in[2];
  const float* mask = (const float*)d_in[3];
  const float* Wq   = (const float*)d_in[4];
  const float* bq   = (const float*)d_in[5];
  const float* Wk   = (const float*)d_in[6];
  const float* bk   = (const float*)d_in[7];
  const float* Wv   = (const float*)d_in[8];
  const float* bv   = (const float*)d_in[9];
  const float* Wp   = (const float*)d_in[10];
  const float* bp   = (const float*)d_in[11];
  const float* rpb  = (const float*)d_in[12];

  char* ws = (char*)d_ws;
  unsigned short* Wq_t   = (unsigned short*)(ws + 0);        //  98,304 B (128x384)
  unsigned short* Wkv_t  = (unsigned short*)(ws + 98304);    // 393,216 B (512x384)
  unsigned short* Wp_t   = (unsigned short*)(ws + 491520);   // 294,912 B
  float*          bias6  = (float*)(ws + 786432);            //  98,304 B
  float*          biaskv = (float*)(ws + 884736);            //   1,920 B
  const size_t MB = 1u << 20;
  unsigned short* q_buf  = (unsigned short*)(ws + MB);                   // 25,165,824 B
  unsigned short* k_buf  = (unsigned short*)(ws + MB + 25165824u);       // 25,165,824 B
  unsigned short* vt_buf = (unsigned short*)(ws + MB + 50331648u);       // 100,663,296 B
  unsigned short* att    = (unsigned short*)(ws + MB + 150994944u);      // 100,663,296 B

  prep_k<<<256, 256, 0, stream>>>(Wq, Wk, Wv, Wp, rpb, rpi, bk, bv,
                                  Wq_t, Wkv_t, Wp_t, bias6, biaskv);
  gws_k<1, 0, 2><<<4096, 256, 0, stream>>>(x, Wq_t, bq, q_buf, nullptr, nullptr);
  gws_k<1, 2, 8><<<16384, 256, 0, stream>>>(cx, Wkv_t, biaskv, nullptr, k_buf, vt_buf);
  attn_k<<<2048, 256, 0, stream>>>(q_buf, k_buf, vt_buf, bias6, mask, att);
  gws_k<0, 1, 6><<<12288, 256, 0, stream>>>(att, Wp_t, bp, d_out, nullptr, nullptr);
}